// Round 1
// baseline (469.936 us; speedup 1.0000x reference)
//
#include <hip/hip_runtime.h>
#include <cstdint>
#include <cstddef>

// GCN 2-layer: out = A_norm * relu(A_norm * (x@W1) + b1) @ W2 ... specifically
//   h  = relu(Agg(x@W1) + b1);  out = Agg(h@W2) + b2
// where Agg(z)[i] = dinv[i] * ( dinv[i]*z[i] + sum_{e: col(e)=i} dinv[row(e)]*z[row(e)] )
// dinv[i] = rsqrt(1 + indegree(i))   (self-loop included)

#define CAP 40  // max in-degree bucket capacity; E/N = 6.4 avg, P(>=40) ~ e^-42

__global__ __launch_bounds__(256) void bucket_fill_kernel(
    const int* __restrict__ rows, const int* __restrict__ cols,
    int* __restrict__ cnt, int* __restrict__ slots, int E, int N) {
  int e = blockIdx.x * 256 + threadIdx.x;
  if (e >= E) return;
  int c = cols[e];
  int r = rows[e];
  if ((unsigned)c >= (unsigned)N || (unsigned)r >= (unsigned)N) return;  // safety
  int pos = atomicAdd(&cnt[c], 1);
  if (pos < CAP) slots[(size_t)c * CAP + pos] = r;
}

__global__ __launch_bounds__(256) void dinv_kernel(
    const int* __restrict__ cnt, float* __restrict__ dinv, int N) {
  int i = blockIdx.x * 256 + threadIdx.x;
  if (i >= N) return;
  dinv[i] = rsqrtf((float)cnt[i] + 1.0f);  // +1 = self-loop
}

// C[M,128] = A[M,128] @ W[128,128], fp32. 128x128 tile per block, 8x8 per thread.
// As stored k-major with pad 129 (stage-write 4-way conflict acceptable; reads clean).
__global__ __launch_bounds__(256) void gemm_kernel(
    const float* __restrict__ A, const float* __restrict__ W,
    float* __restrict__ C, int M) {
  __shared__ float As[128][129];   // 66,048 B
  __shared__ float Ws[128][128];   // 65,536 B  (total 131,584 < 160 KiB)
  const int tid = threadIdx.x;
  const int row0 = blockIdx.x * 128;

  // stage W (contiguous, coalesced)
  {
    const float4* Wg = (const float4*)W;
    float4* Wsv = (float4*)Ws;
#pragma unroll
    for (int i = 0; i < 16; i++) Wsv[tid + i * 256] = Wg[tid + i * 256];
  }
  // stage A transposed: 128 rows x 32 float4 chunks; lanes cover one row -> coalesced
#pragma unroll
  for (int i = 0; i < 16; i++) {
    int c = tid + i * 256;
    int r = c >> 5;          // 0..127
    int k4 = (c & 31) << 2;  // 0,4,...,124
    int gr = row0 + r;
    float4 v = make_float4(0.f, 0.f, 0.f, 0.f);
    if (gr < M) v = ((const float4*)(A + (size_t)gr * 128))[c & 31];
    As[k4 + 0][r] = v.x;
    As[k4 + 1][r] = v.y;
    As[k4 + 2][r] = v.z;
    As[k4 + 3][r] = v.w;
  }
  __syncthreads();

  const int tx = tid & 15;   // col group: cols 4*tx..4*tx+3 and 64+4*tx..
  const int ty = tid >> 4;   // row group: rows 8*ty..8*ty+7
  const int ar = ty * 8;
  const int wc = tx * 4;

  float acc[8][8];
#pragma unroll
  for (int r = 0; r < 8; r++)
#pragma unroll
    for (int c = 0; c < 8; c++) acc[r][c] = 0.f;

#pragma unroll 4
  for (int k = 0; k < 128; k++) {
    float4 a0 = *(const float4*)&As[k][ar];
    float4 a1 = *(const float4*)&As[k][ar + 4];
    float4 w0 = *(const float4*)&Ws[k][wc];
    float4 w1 = *(const float4*)&Ws[k][wc + 64];
    float a[8] = {a0.x, a0.y, a0.z, a0.w, a1.x, a1.y, a1.z, a1.w};
    float w[8] = {w0.x, w0.y, w0.z, w0.w, w1.x, w1.y, w1.z, w1.w};
#pragma unroll
    for (int r = 0; r < 8; r++)
#pragma unroll
      for (int c = 0; c < 8; c++) acc[r][c] = fmaf(a[r], w[c], acc[r][c]);
  }

#pragma unroll
  for (int r = 0; r < 8; r++) {
    int gr = row0 + ar + r;
    if (gr < M) {
      float4* Cr = (float4*)(C + (size_t)gr * 128);
      Cr[tx]      = make_float4(acc[r][0], acc[r][1], acc[r][2], acc[r][3]);
      Cr[16 + tx] = make_float4(acc[r][4], acc[r][5], acc[r][6], acc[r][7]);
    }
  }
}

// One wave per node; lane l owns float2 at cols 2l. Pull-based gather, no atomics.
__global__ __launch_bounds__(256) void aggregate_kernel(
    const float* __restrict__ xw, const int* __restrict__ cnt,
    const int* __restrict__ slots, const float* __restrict__ dinv,
    const float* __restrict__ bias, float* __restrict__ out,
    int N, int do_relu) {
  int node = blockIdx.x * 4 + (threadIdx.x >> 6);
  if (node >= N) return;
  int lane = threadIdx.x & 63;
  const float2* xw2 = (const float2*)xw;

  float di = dinv[node];
  float2 s = xw2[(size_t)node * 64 + lane];
  float accx = di * s.x;   // self-loop term (outer dinv[i] applied at end)
  float accy = di * s.y;

  int c = cnt[node];
  if (c > CAP) c = CAP;
  const int* sl = slots + (size_t)node * CAP;
  for (int e = 0; e < c; e++) {
    int src = sl[e];
    float ds = dinv[src];
    float2 v = xw2[(size_t)src * 64 + lane];
    accx = fmaf(ds, v.x, accx);
    accy = fmaf(ds, v.y, accy);
  }
  float2 bv = ((const float2*)bias)[lane];
  float ox = fmaf(di, accx, bv.x);
  float oy = fmaf(di, accy, bv.y);
  if (do_relu) { ox = fmaxf(ox, 0.f); oy = fmaxf(oy, 0.f); }
  ((float2*)out)[(size_t)node * 64 + lane] = make_float2(ox, oy);
}

extern "C" void kernel_launch(void* const* d_in, const int* in_sizes, int n_in,
                              void* d_out, int out_size, void* d_ws, size_t ws_size,
                              hipStream_t stream) {
  const float* x  = (const float*)d_in[0];
  const int*   ei = (const int*)d_in[1];
  const float* W1 = (const float*)d_in[2];
  const float* b1 = (const float*)d_in[3];
  const float* W2 = (const float*)d_in[4];
  const float* b2 = (const float*)d_in[5];
  float* out = (float*)d_out;

  const int F = 128;
  const int N = in_sizes[0] / F;
  const int E = in_sizes[1] / 2;
  const int* rows = ei;       // edge_index[0] = source
  const int* cols = ei + E;   // edge_index[1] = destination

  // workspace layout
  float* bufA  = (float*)d_ws;                  // N*128 floats (xw scratch)
  float* dinv  = bufA + (size_t)N * F;          // N floats
  int*   cnt   = (int*)(dinv + N);              // N ints
  int*   slots = cnt + N;                       // N*CAP ints

  hipMemsetAsync(cnt, 0, (size_t)N * sizeof(int), stream);
  bucket_fill_kernel<<<(E + 255) / 256, 256, 0, stream>>>(rows, cols, cnt, slots, E, N);
  dinv_kernel<<<(N + 255) / 256, 256, 0, stream>>>(cnt, dinv, N);

  int gblocks = (N + 127) / 128;
  // layer 1: xw1 = x@W1 -> bufA ; h = relu(Agg(xw1)+b1) -> d_out
  gemm_kernel<<<gblocks, 256, 0, stream>>>(x, W1, bufA, N);
  aggregate_kernel<<<(N + 3) / 4, 256, 0, stream>>>(bufA, cnt, slots, dinv, b1, out, N, 1);
  // layer 2: xw2 = h@W2 -> bufA ; out = Agg(xw2)+b2 -> d_out
  gemm_kernel<<<gblocks, 256, 0, stream>>>(out, W2, bufA, N);
  aggregate_kernel<<<(N + 3) / 4, 256, 0, stream>>>(bufA, cnt, slots, dinv, b2, out, N, 0);
}

// Round 3
// 372.009 us; speedup vs baseline: 1.2632x; 1.2632x over previous
//
#include <hip/hip_runtime.h>
#include <cstdint>
#include <cstddef>

// GCN 2-layer:
//   h   = relu(Agg(x@W1) + b1);  out = Agg(h@W2) + b2
//   Agg(z)[i] = dinv[i] * ( dinv[i]*z[i] + sum_{e: col(e)=i} dinv[row(e)]*z[row(e)] )
//   dinv[i] = rsqrt(1 + indeg(i))
// Adjacency built as exact CSR each call (count -> scan -> fill): every adj
// entry read by the aggregate is written this call, by construction.
// Intermediates (xw, h) stored bf16; all accumulation fp32.

typedef unsigned int u32;
typedef unsigned short u16;

__device__ __forceinline__ float bf2f(u32 lo16) {
  union { u32 u; float f; } c; c.u = lo16 << 16; return c.f;
}
__device__ __forceinline__ u32 f2bf(float f) {  // round-to-nearest-even
  union { float f; u32 u; } c; c.f = f;
  return (c.u + 0x7fffu + ((c.u >> 16) & 1u)) >> 16;
}

__global__ __launch_bounds__(256) void zero_i32_kernel(int* __restrict__ p, int n) {
  int i = blockIdx.x * 256 + threadIdx.x;
  if (i < n) p[i] = 0;
}

__global__ __launch_bounds__(256) void count_kernel(
    const int* __restrict__ cols, const int* __restrict__ rows,
    int* __restrict__ cnt, int E, int N) {
  int e = blockIdx.x * 256 + threadIdx.x;
  if (e >= E) return;
  int c = cols[e];
  int r = rows[e];
  if ((unsigned)c >= (unsigned)N || (unsigned)r >= (unsigned)N) return;
  atomicAdd(&cnt[c], 1);
}

__global__ __launch_bounds__(256) void dinv_kernel(
    const int* __restrict__ cnt, float* __restrict__ dinv, int N) {
  int i = blockIdx.x * 256 + threadIdx.x;
  if (i >= N) return;
  dinv[i] = rsqrtf((float)cnt[i] + 1.0f);  // +1 = self-loop
}

// ---- exclusive scan of cnt[N] -> rowptr[N] (rowptr[N] = total, set in pass 2)
// pass 1: per-block (1024 elems) local exclusive scan + block totals
__global__ __launch_bounds__(256) void scan1_kernel(
    const int* __restrict__ cnt, int* __restrict__ rowptr,
    int* __restrict__ bsum, int N) {
  __shared__ int sd[256];
  int t = threadIdx.x;
  int base = blockIdx.x * 1024 + t * 4;
  int c0 = (base + 0 < N) ? cnt[base + 0] : 0;
  int c1 = (base + 1 < N) ? cnt[base + 1] : 0;
  int c2 = (base + 2 < N) ? cnt[base + 2] : 0;
  int c3 = (base + 3 < N) ? cnt[base + 3] : 0;
  int s = c0 + c1 + c2 + c3;
  sd[t] = s;
  __syncthreads();
  for (int off = 1; off < 256; off <<= 1) {
    int v = (t >= off) ? sd[t - off] : 0;
    __syncthreads();
    sd[t] += v;
    __syncthreads();
  }
  int excl = sd[t] - s;  // exclusive within block
  if (base + 0 < N) rowptr[base + 0] = excl;
  if (base + 1 < N) rowptr[base + 1] = excl + c0;
  if (base + 2 < N) rowptr[base + 2] = excl + c0 + c1;
  if (base + 3 < N) rowptr[base + 3] = excl + c0 + c1 + c2;
  if (t == 255) bsum[blockIdx.x] = sd[255];
}

// pass 2: single block scans block totals (NB <= 128); writes rowptr[N]=total
__global__ __launch_bounds__(128) void scan2_kernel(
    const int* __restrict__ bsum, int* __restrict__ bsum2,
    int* __restrict__ rowptr, int NB, int N) {
  __shared__ int sd[128];
  int t = threadIdx.x;
  int v = (t < NB) ? bsum[t] : 0;
  sd[t] = v;
  __syncthreads();
  for (int off = 1; off < 128; off <<= 1) {
    int u = (t >= off) ? sd[t - off] : 0;
    __syncthreads();
    sd[t] += u;
    __syncthreads();
  }
  bsum2[t] = sd[t] - v;  // exclusive
  if (t == NB - 1) rowptr[N] = sd[t];
}

// pass 3: add block offsets
__global__ __launch_bounds__(256) void scan3_kernel(
    int* __restrict__ rowptr, const int* __restrict__ bsum2, int N) {
  int t = threadIdx.x;
  int b = blockIdx.x;
  int base = b * 1024 + t * 4;
  int add = bsum2[b];
#pragma unroll
  for (int k = 0; k < 4; k++)
    if (base + k < N) rowptr[base + k] += add;
}

__global__ __launch_bounds__(256) void fill_kernel(
    const int* __restrict__ cols, const int* __restrict__ rows,
    const int* __restrict__ rowptr, int* __restrict__ cursor,
    int* __restrict__ adj, int E, int N) {
  int e = blockIdx.x * 256 + threadIdx.x;
  if (e >= E) return;
  int c = cols[e];
  int r = rows[e];
  if ((unsigned)c >= (unsigned)N || (unsigned)r >= (unsigned)N) return;
  int pos = atomicAdd(&cursor[c], 1);
  adj[rowptr[c] + pos] = r;
}

// C_bf16[M,128] = A[M,128] @ W[128,128]. fp32 VALU compute.
// 128x128 tile/block, 8x8 per thread, K chunked by 32.
// LDS: As[32][132] (pad 4 keeps rows 16B-aligned -> ds_read_b128) + Ws[32][128]
//      = 33280 B -> 4 blocks/CU (16 waves, 50% occ).
template <int A_BF16>
__global__ __launch_bounds__(256) void gemm_kernel(
    const void* __restrict__ Av, const float* __restrict__ W,
    u16* __restrict__ C, int M) {
  __shared__ float As[32][132];
  __shared__ float Ws[32][128];
  const int tid = threadIdx.x;
  const int row0 = blockIdx.x * 128;

  const int tx = tid & 15;   // cols 4tx..4tx+3 and 64+4tx..64+4tx+3
  const int ty = tid >> 4;   // rows 8ty..8ty+7
  const int ar = ty * 8;
  const int wc = tx * 4;

  float acc[8][8];
#pragma unroll
  for (int r = 0; r < 8; r++)
#pragma unroll
    for (int c = 0; c < 8; c++) acc[r][c] = 0.f;

  for (int k0 = 0; k0 < 128; k0 += 32) {
    __syncthreads();
    {
      const float4* Wg = (const float4*)(W + (size_t)k0 * 128);
      float4* Wsv = (float4*)Ws;
#pragma unroll
      for (int i = 0; i < 4; i++) Wsv[tid + i * 256] = Wg[tid + i * 256];
    }
#pragma unroll
    for (int i = 0; i < 4; i++) {
      int idx = tid + i * 256;     // 0..1023
      int r = idx >> 3;            // 0..127
      int q = idx & 7;             // float4 within 32-col chunk
      int gr = row0 + r;
      float v0 = 0.f, v1 = 0.f, v2 = 0.f, v3 = 0.f;
      if (gr < M) {
        if (A_BF16) {
          const u16* Ab = (const u16*)Av;
          uint2 u = *(const uint2*)(Ab + (size_t)gr * 128 + k0 + q * 4);
          v0 = bf2f(u.x & 0xffff); v1 = bf2f(u.x >> 16);
          v2 = bf2f(u.y & 0xffff); v3 = bf2f(u.y >> 16);
        } else {
          const float* Af = (const float*)Av;
          float4 v = *(const float4*)(Af + (size_t)gr * 128 + k0 + q * 4);
          v0 = v.x; v1 = v.y; v2 = v.z; v3 = v.w;
        }
      }
      As[q * 4 + 0][r] = v0;
      As[q * 4 + 1][r] = v1;
      As[q * 4 + 2][r] = v2;
      As[q * 4 + 3][r] = v3;
    }
    __syncthreads();

#pragma unroll
    for (int k = 0; k < 32; k++) {
      float4 a0 = *(const float4*)&As[k][ar];
      float4 a1 = *(const float4*)&As[k][ar + 4];
      float4 w0 = *(const float4*)&Ws[k][wc];
      float4 w1 = *(const float4*)&Ws[k][wc + 64];
      float a[8] = {a0.x, a0.y, a0.z, a0.w, a1.x, a1.y, a1.z, a1.w};
      float w[8] = {w0.x, w0.y, w0.z, w0.w, w1.x, w1.y, w1.z, w1.w};
#pragma unroll
      for (int r = 0; r < 8; r++)
#pragma unroll
        for (int c = 0; c < 8; c++) acc[r][c] = fmaf(a[r], w[c], acc[r][c]);
    }
  }

#pragma unroll
  for (int r = 0; r < 8; r++) {
    int gr = row0 + ar + r;
    if (gr < M) {
      uint2 p0, p1;
      p0.x = f2bf(acc[r][0]) | (f2bf(acc[r][1]) << 16);
      p0.y = f2bf(acc[r][2]) | (f2bf(acc[r][3]) << 16);
      p1.x = f2bf(acc[r][4]) | (f2bf(acc[r][5]) << 16);
      p1.y = f2bf(acc[r][6]) | (f2bf(acc[r][7]) << 16);
      uint2* Cr = (uint2*)(C + (size_t)gr * 128);
      Cr[tx] = p0;
      Cr[16 + tx] = p1;
    }
  }
}

// One wave per node; lane owns cols {2*lane, 2*lane+1} (one u32 = 2 bf16).
// Pull-based via CSR, no atomics; neighbor loop unrolled x4 for MLP.
// Gathered indices bounds-guarded: garbage can never become an OOB read.
template <int RELU, int OUT_BF16>
__global__ __launch_bounds__(256) void aggregate_kernel(
    const u32* __restrict__ xw, const int* __restrict__ rowptr,
    const int* __restrict__ adj, const float* __restrict__ dinv,
    const float* __restrict__ bias, void* __restrict__ out, int N) {
  int node = blockIdx.x * 4 + (threadIdx.x >> 6);
  if (node >= N) return;
  int lane = threadIdx.x & 63;

  float di = dinv[node];
  u32 sv = xw[(size_t)node * 64 + lane];
  float accx = di * bf2f(sv & 0xffff);  // self-loop (outer di applied at end)
  float accy = di * bf2f(sv >> 16);

  int beg = rowptr[node];
  int end = rowptr[node + 1];
  int j = beg;
  for (; j + 4 <= end; j += 4) {
    int s0 = adj[j], s1 = adj[j + 1], s2 = adj[j + 2], s3 = adj[j + 3];
    float m0 = 1.f, m1 = 1.f, m2 = 1.f, m3 = 1.f;
    if ((unsigned)s0 >= (unsigned)N) { s0 = 0; m0 = 0.f; }
    if ((unsigned)s1 >= (unsigned)N) { s1 = 0; m1 = 0.f; }
    if ((unsigned)s2 >= (unsigned)N) { s2 = 0; m2 = 0.f; }
    if ((unsigned)s3 >= (unsigned)N) { s3 = 0; m3 = 0.f; }
    float d0 = dinv[s0] * m0, d1 = dinv[s1] * m1;
    float d2 = dinv[s2] * m2, d3 = dinv[s3] * m3;
    u32 v0 = xw[(size_t)s0 * 64 + lane];
    u32 v1 = xw[(size_t)s1 * 64 + lane];
    u32 v2 = xw[(size_t)s2 * 64 + lane];
    u32 v3 = xw[(size_t)s3 * 64 + lane];
    accx = fmaf(d0, bf2f(v0 & 0xffff), accx); accy = fmaf(d0, bf2f(v0 >> 16), accy);
    accx = fmaf(d1, bf2f(v1 & 0xffff), accx); accy = fmaf(d1, bf2f(v1 >> 16), accy);
    accx = fmaf(d2, bf2f(v2 & 0xffff), accx); accy = fmaf(d2, bf2f(v2 >> 16), accy);
    accx = fmaf(d3, bf2f(v3 & 0xffff), accx); accy = fmaf(d3, bf2f(v3 >> 16), accy);
  }
  for (; j < end; j++) {
    int s = adj[j];
    float m = 1.f;
    if ((unsigned)s >= (unsigned)N) { s = 0; m = 0.f; }
    float ds = dinv[s] * m;
    u32 v = xw[(size_t)s * 64 + lane];
    accx = fmaf(ds, bf2f(v & 0xffff), accx);
    accy = fmaf(ds, bf2f(v >> 16), accy);
  }

  float2 bv = ((const float2*)bias)[lane];
  float ox = fmaf(di, accx, bv.x);
  float oy = fmaf(di, accy, bv.y);
  if (RELU) { ox = fmaxf(ox, 0.f); oy = fmaxf(oy, 0.f); }
  if (OUT_BF16) {
    ((u32*)out)[(size_t)node * 64 + lane] = f2bf(ox) | (f2bf(oy) << 16);
  } else {
    ((float2*)out)[(size_t)node * 64 + lane] = make_float2(ox, oy);
  }
}

extern "C" void kernel_launch(void* const* d_in, const int* in_sizes, int n_in,
                              void* d_out, int out_size, void* d_ws, size_t ws_size,
                              hipStream_t stream) {
  const float* x  = (const float*)d_in[0];
  const int*   ei = (const int*)d_in[1];
  const float* W1 = (const float*)d_in[2];
  const float* b1 = (const float*)d_in[3];
  const float* W2 = (const float*)d_in[4];
  const float* b2 = (const float*)d_in[5];
  float* out = (float*)d_out;

  const int F = 128;
  const int N = in_sizes[0] / F;
  const int E = in_sizes[1] / 2;
  const int* rows = ei;       // edge_index[0] = source
  const int* cols = ei + E;   // edge_index[1] = destination

  // workspace layout (~55 MB)
  u16*   bufXW  = (u16*)d_ws;                      // N*128 bf16
  u16*   bufH   = bufXW + (size_t)N * F;           // N*128 bf16
  float* dinv   = (float*)(bufH + (size_t)N * F);  // N f32
  int*   cnt    = (int*)(dinv + N);                // N i32 (count, then cursor)
  int*   rowptr = cnt + N;                         // N+1 i32
  int*   adj    = rowptr + (N + 1);                // E i32
  int*   bsum   = adj + E;                         // 128 i32
  int*   bsum2  = bsum + 128;                      // 128 i32

  const int NB = (N + 1023) / 1024;  // scan blocks (<=128 for N<=131072)
  int eblocks = (E + 255) / 256;
  int nblocks = (N + 255) / 256;

  // build exact CSR
  zero_i32_kernel<<<nblocks, 256, 0, stream>>>(cnt, N);
  count_kernel<<<eblocks, 256, 0, stream>>>(cols, rows, cnt, E, N);
  dinv_kernel<<<nblocks, 256, 0, stream>>>(cnt, dinv, N);
  scan1_kernel<<<NB, 256, 0, stream>>>(cnt, rowptr, bsum, N);
  scan2_kernel<<<1, 128, 0, stream>>>(bsum, bsum2, rowptr, NB, N);
  scan3_kernel<<<NB, 256, 0, stream>>>(rowptr, bsum2, N);
  zero_i32_kernel<<<nblocks, 256, 0, stream>>>(cnt, N);  // reuse as cursor
  fill_kernel<<<eblocks, 256, 0, stream>>>(cols, rows, rowptr, cnt, adj, E, N);

  int gblocks = (N + 127) / 128;
  int ablocks = (N + 3) / 4;
  // layer 1: xw1 = x@W1 (bf16) ; h = relu(Agg(xw1)+b1) -> bufH (bf16)
  gemm_kernel<0><<<gblocks, 256, 0, stream>>>(x, W1, bufXW, N);
  aggregate_kernel<1, 1><<<ablocks, 256, 0, stream>>>(
      (const u32*)bufXW, rowptr, adj, dinv, b1, bufH, N);
  // layer 2: xw2 = h@W2 (bf16) ; out = Agg(xw2)+b2 -> d_out (fp32)
  gemm_kernel<1><<<gblocks, 256, 0, stream>>>(bufH, W2, bufXW, N);
  aggregate_kernel<0, 0><<<ablocks, 256, 0, stream>>>(
      (const u32*)bufXW, rowptr, adj, dinv, b2, out, N);
}

// Round 4
// 292.478 us; speedup vs baseline: 1.6067x; 1.2719x over previous
//
#include <hip/hip_runtime.h>
#include <cstdint>
#include <cstddef>

// GCN 2-layer:
//   h   = relu(Agg(x@W1) + b1);  out = Agg(h@W2) + b2
//   Agg(z)[i] = dinv[i] * ( dinv[i]*z[i] + sum_{e: col(e)=i} dinv[row(e)]*z[row(e)] )
//   dinv[i] = rsqrt(1 + indeg(i))
// Factorization used here: xws = dinv ⊙ (A@W) (scaled in GEMM epilogue, bf16);
//   Agg reduces to out[i] = dinv[i]*(xws[i] + Σ_{nbr r} xws[r]) + b  — no per-edge
//   dinv gather. GEMM runs on MFMA (bf16 in, fp32 acc). CSR built exactly each
//   call (count -> scan -> fill): no uninitialized adj reads possible.

typedef unsigned int u32;
typedef unsigned short u16;
typedef __attribute__((ext_vector_type(8))) short short8;   // 8 bf16 (4 VGPRs)
typedef __attribute__((ext_vector_type(4))) float f32x4;    // MFMA acc

__device__ __forceinline__ float bf2f(u32 lo16) {
  union { u32 u; float f; } c; c.u = lo16 << 16; return c.f;
}
__device__ __forceinline__ u32 f2bf(float f) {  // round-to-nearest-even
  union { float f; u32 u; } c; c.f = f;
  return (c.u + 0x7fffu + ((c.u >> 16) & 1u)) >> 16;
}

__global__ __launch_bounds__(256) void zero_i32_kernel(int* __restrict__ p, int n) {
  int i = blockIdx.x * 256 + threadIdx.x;
  if (i < n) p[i] = 0;
}

__global__ __launch_bounds__(256) void count_kernel(
    const int* __restrict__ cols, const int* __restrict__ rows,
    int* __restrict__ cnt, int E, int N) {
  int e = blockIdx.x * 256 + threadIdx.x;
  if (e >= E) return;
  int c = cols[e];
  int r = rows[e];
  if ((unsigned)c >= (unsigned)N || (unsigned)r >= (unsigned)N) return;
  atomicAdd(&cnt[c], 1);
}

__global__ __launch_bounds__(256) void dinv_kernel(
    const int* __restrict__ cnt, float* __restrict__ dinv, int N) {
  int i = blockIdx.x * 256 + threadIdx.x;
  if (i >= N) return;
  dinv[i] = rsqrtf((float)cnt[i] + 1.0f);  // +1 = self-loop
}

// W[k][n] fp32 -> Wt[n][k] bf16 (row-major [128][128])
__global__ __launch_bounds__(256) void wt_kernel(
    const float* __restrict__ W, u16* __restrict__ Wt) {
  int idx = blockIdx.x * 256 + threadIdx.x;  // 0..16383
  int k = idx >> 7, n = idx & 127;
  Wt[n * 128 + k] = (u16)f2bf(W[idx]);
}

// ---- exclusive scan of cnt[N] -> rowptr[N] (rowptr[N]=total, set in pass 2)
__global__ __launch_bounds__(256) void scan1_kernel(
    const int* __restrict__ cnt, int* __restrict__ rowptr,
    int* __restrict__ bsum, int N) {
  __shared__ int sd[256];
  int t = threadIdx.x;
  int base = blockIdx.x * 1024 + t * 4;
  int c0 = (base + 0 < N) ? cnt[base + 0] : 0;
  int c1 = (base + 1 < N) ? cnt[base + 1] : 0;
  int c2 = (base + 2 < N) ? cnt[base + 2] : 0;
  int c3 = (base + 3 < N) ? cnt[base + 3] : 0;
  int s = c0 + c1 + c2 + c3;
  sd[t] = s;
  __syncthreads();
  for (int off = 1; off < 256; off <<= 1) {
    int v = (t >= off) ? sd[t - off] : 0;
    __syncthreads();
    sd[t] += v;
    __syncthreads();
  }
  int excl = sd[t] - s;
  if (base + 0 < N) rowptr[base + 0] = excl;
  if (base + 1 < N) rowptr[base + 1] = excl + c0;
  if (base + 2 < N) rowptr[base + 2] = excl + c0 + c1;
  if (base + 3 < N) rowptr[base + 3] = excl + c0 + c1 + c2;
  if (t == 255) bsum[blockIdx.x] = sd[255];
}

__global__ __launch_bounds__(128) void scan2_kernel(
    const int* __restrict__ bsum, int* __restrict__ bsum2,
    int* __restrict__ rowptr, int NB, int N) {
  __shared__ int sd[128];
  int t = threadIdx.x;
  int v = (t < NB) ? bsum[t] : 0;
  sd[t] = v;
  __syncthreads();
  for (int off = 1; off < 128; off <<= 1) {
    int u = (t >= off) ? sd[t - off] : 0;
    __syncthreads();
    sd[t] += u;
    __syncthreads();
  }
  bsum2[t] = sd[t] - v;
  if (t == NB - 1) rowptr[N] = sd[t];
}

__global__ __launch_bounds__(256) void scan3_kernel(
    int* __restrict__ rowptr, const int* __restrict__ bsum2, int N) {
  int t = threadIdx.x;
  int b = blockIdx.x;
  int base = b * 1024 + t * 4;
  int add = bsum2[b];
#pragma unroll
  for (int k = 0; k < 4; k++)
    if (base + k < N) rowptr[base + k] += add;
}

__global__ __launch_bounds__(256) void fill_kernel(
    const int* __restrict__ cols, const int* __restrict__ rows,
    const int* __restrict__ rowptr, int* __restrict__ cursor,
    int* __restrict__ adj, int E, int N) {
  int e = blockIdx.x * 256 + threadIdx.x;
  if (e >= E) return;
  int c = cols[e];
  int r = rows[e];
  if ((unsigned)c >= (unsigned)N || (unsigned)r >= (unsigned)N) return;
  int pos = atomicAdd(&cursor[c], 1);
  adj[rowptr[c] + pos] = r;
}

// C_bf16[M,128] = dinv[row] * (A[M,128] @ W[128,128]) via MFMA 16x16x32 bf16.
// Block = 256 thr (4 waves), tile 128 rows; wave w owns rows w*32..w*32+31
// (2 m-tiles of 16) x all 128 cols (8 n-tiles of 16). W staged once in LDS as
// Wt[n][k] bf16 padded to 136 (2-way bank aliasing only -> free). A fragments
// loaded straight from global (each element read exactly once; no k-loop
// barrier). Fragment layouts (m89/m118-verified):
//   A: lane holds A[m=lane&15][k=quad*8+j], j=0..7
//   B: lane holds B[k=quad*8+j][n=lane&15]
//   C/D: col=lane&15, row=quad*4+reg
template <int A_BF16>
__global__ __launch_bounds__(256) void gemm_mfma_kernel(
    const void* __restrict__ Av, const u16* __restrict__ Wt,
    const float* __restrict__ dinv, u16* __restrict__ C, int M) {
  __shared__ u16 Ws[128][136];
  __shared__ float dv_s[128];
  const int tid = threadIdx.x;
  const int row0 = blockIdx.x * 128;

  // stage Wt (16B chunks); one-time, minor conflicts irrelevant
  {
    const uint4* src = (const uint4*)Wt;  // 2048 x 16B
#pragma unroll
    for (int i = 0; i < 8; i++) {
      int linear = tid + i * 256;
      int n = linear >> 4;
      int kq = linear & 15;
      *(uint4*)&Ws[n][kq * 8] = src[linear];
    }
  }
  if (tid < 128) {
    int gr = row0 + tid;
    dv_s[tid] = (gr < M) ? dinv[gr] : 0.f;
  }
  __syncthreads();

  const int wave = tid >> 6;
  const int lane = tid & 63;
  const int lm = lane & 15;
  const int quad = lane >> 4;
  const int m0 = wave * 32;

  f32x4 acc[2][8];
#pragma unroll
  for (int mt = 0; mt < 2; mt++)
#pragma unroll
    for (int nt = 0; nt < 8; nt++) acc[mt][nt] = (f32x4){0.f, 0.f, 0.f, 0.f};

#pragma unroll
  for (int k0 = 0; k0 < 128; k0 += 32) {
    short8 bfrag[8];
#pragma unroll
    for (int nt = 0; nt < 8; nt++)
      bfrag[nt] = *(const short8*)&Ws[nt * 16 + lm][k0 + quad * 8];

    short8 afrag[2];
#pragma unroll
    for (int mt = 0; mt < 2; mt++) {
      int gr = row0 + m0 + mt * 16 + lm;
      short8 f = (short8){0, 0, 0, 0, 0, 0, 0, 0};
      if (gr < M) {
        if (A_BF16) {
          f = *(const short8*)((const u16*)Av + (size_t)gr * 128 + k0 + quad * 8);
        } else {
          const float* Af = (const float*)Av + (size_t)gr * 128 + k0 + quad * 8;
          float4 v0 = *(const float4*)Af;
          float4 v1 = *(const float4*)(Af + 4);
          f[0] = (short)f2bf(v0.x); f[1] = (short)f2bf(v0.y);
          f[2] = (short)f2bf(v0.z); f[3] = (short)f2bf(v0.w);
          f[4] = (short)f2bf(v1.x); f[5] = (short)f2bf(v1.y);
          f[6] = (short)f2bf(v1.z); f[7] = (short)f2bf(v1.w);
        }
      }
      afrag[mt] = f;
    }

#pragma unroll
    for (int mt = 0; mt < 2; mt++)
#pragma unroll
      for (int nt = 0; nt < 8; nt++)
        acc[mt][nt] = __builtin_amdgcn_mfma_f32_16x16x32_bf16(
            afrag[mt], bfrag[nt], acc[mt][nt], 0, 0, 0);
  }

  // epilogue: scale by dinv[row], pack bf16
#pragma unroll
  for (int mt = 0; mt < 2; mt++) {
    int rbase = m0 + mt * 16 + quad * 4;
#pragma unroll
    for (int r = 0; r < 4; r++) {
      int lrow = rbase + r;
      int grow = row0 + lrow;
      if (grow < M) {
        float dv = dv_s[lrow];
        u16* Crow = C + (size_t)grow * 128 + lm;
#pragma unroll
        for (int nt = 0; nt < 8; nt++)
          Crow[nt * 16] = (u16)f2bf(acc[mt][nt][r] * dv);
      }
    }
  }
}

// One wave per node; lane owns cols {2*lane, 2*lane+1} (one u32 = 2 bf16).
// xws already carries dinv[src]; per-neighbor work = 1 gather + 2 adds.
template <int RELU, int OUT_BF16>
__global__ __launch_bounds__(256) void aggregate_kernel(
    const u32* __restrict__ xws, const int* __restrict__ rowptr,
    const int* __restrict__ adj, const float* __restrict__ dinv,
    const float* __restrict__ bias, void* __restrict__ out, int N) {
  int node = blockIdx.x * 4 + (threadIdx.x >> 6);
  if (node >= N) return;
  int lane = threadIdx.x & 63;

  u32 sv = xws[(size_t)node * 64 + lane];
  float accx = bf2f(sv & 0xffff);  // self term (xws already dinv-scaled)
  float accy = bf2f(sv >> 16);

  int beg = rowptr[node];
  int end = rowptr[node + 1];
  int j = beg;
  for (; j + 4 <= end; j += 4) {
    int s0 = adj[j], s1 = adj[j + 1], s2 = adj[j + 2], s3 = adj[j + 3];
    float m0 = 1.f, m1 = 1.f, m2 = 1.f, m3 = 1.f;
    if ((unsigned)s0 >= (unsigned)N) { s0 = 0; m0 = 0.f; }
    if ((unsigned)s1 >= (unsigned)N) { s1 = 0; m1 = 0.f; }
    if ((unsigned)s2 >= (unsigned)N) { s2 = 0; m2 = 0.f; }
    if ((unsigned)s3 >= (unsigned)N) { s3 = 0; m3 = 0.f; }
    u32 v0 = xws[(size_t)s0 * 64 + lane];
    u32 v1 = xws[(size_t)s1 * 64 + lane];
    u32 v2 = xws[(size_t)s2 * 64 + lane];
    u32 v3 = xws[(size_t)s3 * 64 + lane];
    accx = fmaf(m0, bf2f(v0 & 0xffff), accx); accy = fmaf(m0, bf2f(v0 >> 16), accy);
    accx = fmaf(m1, bf2f(v1 & 0xffff), accx); accy = fmaf(m1, bf2f(v1 >> 16), accy);
    accx = fmaf(m2, bf2f(v2 & 0xffff), accx); accy = fmaf(m2, bf2f(v2 >> 16), accy);
    accx = fmaf(m3, bf2f(v3 & 0xffff), accx); accy = fmaf(m3, bf2f(v3 >> 16), accy);
  }
  for (; j < end; j++) {
    int s = adj[j];
    float m = 1.f;
    if ((unsigned)s >= (unsigned)N) { s = 0; m = 0.f; }
    u32 v = xws[(size_t)s * 64 + lane];
    accx = fmaf(m, bf2f(v & 0xffff), accx);
    accy = fmaf(m, bf2f(v >> 16), accy);
  }

  float di = dinv[node];
  float2 bv = ((const float2*)bias)[lane];
  float ox = fmaf(di, accx, bv.x);
  float oy = fmaf(di, accy, bv.y);
  if (RELU) { ox = fmaxf(ox, 0.f); oy = fmaxf(oy, 0.f); }
  if (OUT_BF16) {
    ((u32*)out)[(size_t)node * 64 + lane] = f2bf(ox) | (f2bf(oy) << 16);
  } else {
    ((float2*)out)[(size_t)node * 64 + lane] = make_float2(ox, oy);
  }
}

extern "C" void kernel_launch(void* const* d_in, const int* in_sizes, int n_in,
                              void* d_out, int out_size, void* d_ws, size_t ws_size,
                              hipStream_t stream) {
  const float* x  = (const float*)d_in[0];
  const int*   ei = (const int*)d_in[1];
  const float* W1 = (const float*)d_in[2];
  const float* b1 = (const float*)d_in[3];
  const float* W2 = (const float*)d_in[4];
  const float* b2 = (const float*)d_in[5];
  float* out = (float*)d_out;

  const int F = 128;
  const int N = in_sizes[0] / F;
  const int E = in_sizes[1] / 2;
  const int* rows = ei;       // edge_index[0] = source
  const int* cols = ei + E;   // edge_index[1] = destination

  // workspace layout (~55 MB)
  u16*   bufXW  = (u16*)d_ws;                      // N*128 bf16 (xws scratch)
  u16*   bufH   = bufXW + (size_t)N * F;           // N*128 bf16 (h)
  float* dinv   = (float*)(bufH + (size_t)N * F);  // N f32
  int*   cnt    = (int*)(dinv + N);                // N i32 (count, then cursor)
  int*   rowptr = cnt + N;                         // N+1 i32
  int*   adj    = rowptr + (N + 1);                // E i32
  int*   bsum   = adj + E;                         // 128 i32
  int*   bsum2  = bsum + 128;                      // 128 i32
  u16*   Wt1    = (u16*)(bsum2 + 128);             // 128*128 bf16 (W1^T)
  u16*   Wt2    = Wt1 + 128 * 128;                 // 128*128 bf16 (W2^T)

  const int NB = (N + 1023) / 1024;
  int eblocks = (E + 255) / 256;
  int nblocks = (N + 255) / 256;

  // build exact CSR + dinv; transpose/convert weights
  zero_i32_kernel<<<nblocks, 256, 0, stream>>>(cnt, N);
  count_kernel<<<eblocks, 256, 0, stream>>>(cols, rows, cnt, E, N);
  dinv_kernel<<<nblocks, 256, 0, stream>>>(cnt, dinv, N);
  scan1_kernel<<<NB, 256, 0, stream>>>(cnt, rowptr, bsum, N);
  scan2_kernel<<<1, 128, 0, stream>>>(bsum, bsum2, rowptr, NB, N);
  scan3_kernel<<<NB, 256, 0, stream>>>(rowptr, bsum2, N);
  zero_i32_kernel<<<nblocks, 256, 0, stream>>>(cnt, N);  // reuse as cursor
  fill_kernel<<<eblocks, 256, 0, stream>>>(cols, rows, rowptr, cnt, adj, E, N);
  wt_kernel<<<64, 256, 0, stream>>>(W1, Wt1);
  wt_kernel<<<64, 256, 0, stream>>>(W2, Wt2);

  int gblocks = (N + 127) / 128;
  int ablocks = (N + 3) / 4;
  // layer 1: xws1 = dinv ⊙ (x@W1) (bf16) ; h = relu(dinv⊙Σ + b1) -> bufH (bf16)
  gemm_mfma_kernel<0><<<gblocks, 256, 0, stream>>>(x, Wt1, dinv, bufXW, N);
  aggregate_kernel<1, 1><<<ablocks, 256, 0, stream>>>(
      (const u32*)bufXW, rowptr, adj, dinv, b1, bufH, N);
  // layer 2: xws2 = dinv ⊙ (h@W2) (bf16) ; out = dinv⊙Σ + b2 -> d_out (fp32)
  gemm_mfma_kernel<1><<<gblocks, 256, 0, stream>>>(bufH, Wt2, dinv, bufXW, N);
  aggregate_kernel<0, 0><<<ablocks, 256, 0, stream>>>(
      (const u32*)bufXW, rowptr, adj, dinv, b2, out, N);
}

// Round 5
// 270.353 us; speedup vs baseline: 1.7382x; 1.0818x over previous
//
#include <hip/hip_runtime.h>
#include <cstdint>
#include <cstddef>

// GCN 2-layer:
//   h   = relu(Agg(x@W1) + b1);  out = Agg(h@W2) + b2
//   Agg(z)[i] = dinv[i] * ( dinv[i]*z[i] + sum_{e: col(e)=i} dinv[row(e)]*z[row(e)] )
//   dinv[i] = rsqrt(1 + indeg(i))
// Factorization: xws = dinv ⊙ (A@W) (scaled in GEMM epilogue, bf16);
//   Agg reduces to out[i] = dinv[i]*(xws[i] + Σ_{nbr r} xws[r]) + b.
// GEMM on MFMA (bf16 in, fp32 acc), coalesced epilogue via LDS transpose.
// CSR built exactly each call (count -> scan -> fill) -> no uninit adj reads.

typedef unsigned int u32;
typedef unsigned short u16;
typedef __attribute__((ext_vector_type(8))) short short8;   // 8 bf16 (4 VGPRs)
typedef __attribute__((ext_vector_type(4))) float f32x4;    // MFMA acc

__device__ __forceinline__ float bf2f(u32 lo16) {
  union { u32 u; float f; } c; c.u = lo16 << 16; return c.f;
}
__device__ __forceinline__ u32 f2bf(float f) {  // round-to-nearest-even
  union { float f; u32 u; } c; c.f = f;
  return (c.u + 0x7fffu + ((c.u >> 16) & 1u)) >> 16;
}

__global__ __launch_bounds__(256) void zero_i32_kernel(int* __restrict__ p, int n) {
  int i = blockIdx.x * 256 + threadIdx.x;
  if (i < n) p[i] = 0;
}

__global__ __launch_bounds__(256) void count_kernel(
    const int* __restrict__ cols, const int* __restrict__ rows,
    int* __restrict__ cnt, int E, int N) {
  int e = blockIdx.x * 256 + threadIdx.x;
  if (e >= E) return;
  int c = cols[e];
  int r = rows[e];
  if ((unsigned)c >= (unsigned)N || (unsigned)r >= (unsigned)N) return;
  atomicAdd(&cnt[c], 1);
}

// W1,W2 [k][n] fp32 -> Wt1,Wt2 [n][k] bf16, one launch (128 blocks)
__global__ __launch_bounds__(256) void wt_kernel(
    const float* __restrict__ W1, const float* __restrict__ W2,
    u16* __restrict__ Wt1, u16* __restrict__ Wt2) {
  int b = blockIdx.x;
  const float* W = (b < 64) ? W1 : W2;
  u16* Wt = (b < 64) ? Wt1 : Wt2;
  int idx = (b & 63) * 256 + threadIdx.x;  // 0..16383
  int k = idx >> 7, n = idx & 127;
  Wt[n * 128 + k] = (u16)f2bf(W[idx]);
}

// ---- exclusive scan of cnt[N] -> rowptr[N]; also emits dinv (fused)
__global__ __launch_bounds__(256) void scan1_kernel(
    const int* __restrict__ cnt, int* __restrict__ rowptr,
    int* __restrict__ bsum, float* __restrict__ dinv, int N) {
  __shared__ int sd[256];
  int t = threadIdx.x;
  int base = blockIdx.x * 1024 + t * 4;
  int c0 = (base + 0 < N) ? cnt[base + 0] : 0;
  int c1 = (base + 1 < N) ? cnt[base + 1] : 0;
  int c2 = (base + 2 < N) ? cnt[base + 2] : 0;
  int c3 = (base + 3 < N) ? cnt[base + 3] : 0;
  if (base + 0 < N) dinv[base + 0] = rsqrtf((float)c0 + 1.0f);
  if (base + 1 < N) dinv[base + 1] = rsqrtf((float)c1 + 1.0f);
  if (base + 2 < N) dinv[base + 2] = rsqrtf((float)c2 + 1.0f);
  if (base + 3 < N) dinv[base + 3] = rsqrtf((float)c3 + 1.0f);
  int s = c0 + c1 + c2 + c3;
  sd[t] = s;
  __syncthreads();
  for (int off = 1; off < 256; off <<= 1) {
    int v = (t >= off) ? sd[t - off] : 0;
    __syncthreads();
    sd[t] += v;
    __syncthreads();
  }
  int excl = sd[t] - s;
  if (base + 0 < N) rowptr[base + 0] = excl;
  if (base + 1 < N) rowptr[base + 1] = excl + c0;
  if (base + 2 < N) rowptr[base + 2] = excl + c0 + c1;
  if (base + 3 < N) rowptr[base + 3] = excl + c0 + c1 + c2;
  if (t == 255) bsum[blockIdx.x] = sd[255];
}

__global__ __launch_bounds__(128) void scan2_kernel(
    const int* __restrict__ bsum, int* __restrict__ bsum2,
    int* __restrict__ rowptr, int NB, int N) {
  __shared__ int sd[128];
  int t = threadIdx.x;
  int v = (t < NB) ? bsum[t] : 0;
  sd[t] = v;
  __syncthreads();
  for (int off = 1; off < 128; off <<= 1) {
    int u = (t >= off) ? sd[t - off] : 0;
    __syncthreads();
    sd[t] += u;
    __syncthreads();
  }
  bsum2[t] = sd[t] - v;
  if (t == NB - 1) rowptr[N] = sd[t];
}

__global__ __launch_bounds__(256) void scan3_kernel(
    int* __restrict__ rowptr, const int* __restrict__ bsum2, int N) {
  int t = threadIdx.x;
  int b = blockIdx.x;
  int base = b * 1024 + t * 4;
  int add = bsum2[b];
#pragma unroll
  for (int k = 0; k < 4; k++)
    if (base + k < N) rowptr[base + k] += add;
}

// cnt doubles as the cursor: atomicSub returns old count, pos = old-1 in [0,deg)
__global__ __launch_bounds__(256) void fill_kernel(
    const int* __restrict__ cols, const int* __restrict__ rows,
    const int* __restrict__ rowptr, int* __restrict__ cnt,
    int* __restrict__ adj, int E, int N) {
  int e = blockIdx.x * 256 + threadIdx.x;
  if (e >= E) return;
  int c = cols[e];
  int r = rows[e];
  if ((unsigned)c >= (unsigned)N || (unsigned)r >= (unsigned)N) return;
  int pos = atomicSub(&cnt[c], 1) - 1;
  if (pos >= 0) adj[rowptr[c] + pos] = r;
}

// C_bf16[M,128] = dinv[row] * (A[M,128] @ W[128,128]) via MFMA 16x16x32 bf16.
// Block = 256 thr (4 waves), tile 128 rows; wave w owns rows w*32..+31
// (2 m-tiles) x 128 cols (8 n-tiles). Wt staged once in LDS [n][k] pad 136.
// A fragments straight from global (each byte read once; no k-loop barrier).
// Epilogue: scaled bf16 tile round-trips through Ws (dead after k-loop) so
// global stores are coalesced uint4 (was: 64 scalar 2B stores/lane).
// Fragment layouts (m89/m118-verified):
//   A: lane holds A[m=lane&15][k=quad*8+j];  B: B[k=quad*8+j][n=lane&15]
//   C/D: col=lane&15, row=quad*4+reg
template <int A_BF16>
__global__ __launch_bounds__(256) void gemm_mfma_kernel(
    const void* __restrict__ Av, const u16* __restrict__ Wt,
    const float* __restrict__ dinv, u16* __restrict__ C, int M) {
  __shared__ u16 Ws[128][136];
  __shared__ float dv_s[128];
  const int tid = threadIdx.x;
  const int row0 = blockIdx.x * 128;

  {
    const uint4* src = (const uint4*)Wt;  // 2048 x 16B
#pragma unroll
    for (int i = 0; i < 8; i++) {
      int linear = tid + i * 256;
      int n = linear >> 4;
      int kq = linear & 15;
      *(uint4*)&Ws[n][kq * 8] = src[linear];
    }
  }
  if (tid < 128) {
    int gr = row0 + tid;
    dv_s[tid] = (gr < M) ? dinv[gr] : 0.f;
  }
  __syncthreads();

  const int wave = tid >> 6;
  const int lane = tid & 63;
  const int lm = lane & 15;
  const int quad = lane >> 4;
  const int m0 = wave * 32;

  f32x4 acc[2][8];
#pragma unroll
  for (int mt = 0; mt < 2; mt++)
#pragma unroll
    for (int nt = 0; nt < 8; nt++) acc[mt][nt] = (f32x4){0.f, 0.f, 0.f, 0.f};

#pragma unroll
  for (int k0 = 0; k0 < 128; k0 += 32) {
    short8 bfrag[8];
#pragma unroll
    for (int nt = 0; nt < 8; nt++)
      bfrag[nt] = *(const short8*)&Ws[nt * 16 + lm][k0 + quad * 8];

    short8 afrag[2];
#pragma unroll
    for (int mt = 0; mt < 2; mt++) {
      int gr = row0 + m0 + mt * 16 + lm;
      short8 f = (short8){0, 0, 0, 0, 0, 0, 0, 0};
      if (gr < M) {
        if (A_BF16) {
          f = *(const short8*)((const u16*)Av + (size_t)gr * 128 + k0 + quad * 8);
        } else {
          const float* Af = (const float*)Av + (size_t)gr * 128 + k0 + quad * 8;
          float4 v0 = *(const float4*)Af;
          float4 v1 = *(const float4*)(Af + 4);
          f[0] = (short)f2bf(v0.x); f[1] = (short)f2bf(v0.y);
          f[2] = (short)f2bf(v0.z); f[3] = (short)f2bf(v0.w);
          f[4] = (short)f2bf(v1.x); f[5] = (short)f2bf(v1.y);
          f[6] = (short)f2bf(v1.z); f[7] = (short)f2bf(v1.w);
        }
      }
      afrag[mt] = f;
    }

#pragma unroll
    for (int mt = 0; mt < 2; mt++)
#pragma unroll
      for (int nt = 0; nt < 8; nt++)
        acc[mt][nt] = __builtin_amdgcn_mfma_f32_16x16x32_bf16(
            afrag[mt], bfrag[nt], acc[mt][nt], 0, 0, 0);
  }

  // epilogue: scale by dinv[row], pack bf16 into Ws (dead), store coalesced
  __syncthreads();  // all waves done reading Ws
#pragma unroll
  for (int mt = 0; mt < 2; mt++) {
    int rbase = m0 + mt * 16 + quad * 4;
#pragma unroll
    for (int r = 0; r < 4; r++) {
      int lrow = rbase + r;
      float dv = dv_s[lrow];
#pragma unroll
      for (int nt = 0; nt < 8; nt++)
        Ws[lrow][nt * 16 + lm] = (u16)f2bf(acc[mt][nt][r] * dv);
    }
  }
  __syncthreads();
#pragma unroll
  for (int i = 0; i < 8; i++) {
    int linear = tid + i * 256;  // 0..2047
    int row = linear >> 4;
    int c8 = linear & 15;        // 8-col chunk
    int grow = row0 + row;
    if (grow < M)
      *(uint4*)(C + (size_t)grow * 128 + c8 * 8) = *(const uint4*)&Ws[row][c8 * 8];
  }
}

// Half-wave (32 lanes) per node; lane owns cols 4l..4l+3 (uint2 = 4 bf16).
// 2 independent node chains per wave + unroll-8 -> deep MLP on the gather.
template <int RELU, int OUT_BF16>
__global__ __launch_bounds__(256) void aggregate_kernel(
    const uint2* __restrict__ xws, const int* __restrict__ rowptr,
    const int* __restrict__ adj, const float* __restrict__ dinv,
    const float* __restrict__ bias, void* __restrict__ out, int N) {
  int node = blockIdx.x * 8 + (threadIdx.x >> 5);
  if (node >= N) return;
  int lane = threadIdx.x & 31;

  uint2 sv = xws[(size_t)node * 32 + lane];
  float a0 = bf2f(sv.x & 0xffff), a1 = bf2f(sv.x >> 16);
  float a2 = bf2f(sv.y & 0xffff), a3 = bf2f(sv.y >> 16);

  int beg = rowptr[node];
  int end = rowptr[node + 1];
  for (int j = beg; j < end; j += 8) {
    int sidx[8];
    float msk[8];
#pragma unroll
    for (int k = 0; k < 8; k++) {
      int jj = j + k;
      int s = (jj < end) ? adj[jj] : -1;
      float m = 1.f;
      if ((unsigned)s >= (unsigned)N) { s = 0; m = 0.f; }
      sidx[k] = s;
      msk[k] = m;
    }
    uint2 v[8];
#pragma unroll
    for (int k = 0; k < 8; k++) v[k] = xws[(size_t)sidx[k] * 32 + lane];
#pragma unroll
    for (int k = 0; k < 8; k++) {
      a0 = fmaf(msk[k], bf2f(v[k].x & 0xffff), a0);
      a1 = fmaf(msk[k], bf2f(v[k].x >> 16), a1);
      a2 = fmaf(msk[k], bf2f(v[k].y & 0xffff), a2);
      a3 = fmaf(msk[k], bf2f(v[k].y >> 16), a3);
    }
  }

  float di = dinv[node];
  float4 bv = ((const float4*)bias)[lane];
  float o0 = fmaf(di, a0, bv.x);
  float o1 = fmaf(di, a1, bv.y);
  float o2 = fmaf(di, a2, bv.z);
  float o3 = fmaf(di, a3, bv.w);
  if (RELU) {
    o0 = fmaxf(o0, 0.f); o1 = fmaxf(o1, 0.f);
    o2 = fmaxf(o2, 0.f); o3 = fmaxf(o3, 0.f);
  }
  if (OUT_BF16) {
    uint2 p;
    p.x = f2bf(o0) | (f2bf(o1) << 16);
    p.y = f2bf(o2) | (f2bf(o3) << 16);
    ((uint2*)out)[(size_t)node * 32 + lane] = p;
  } else {
    ((float4*)out)[(size_t)node * 32 + lane] = make_float4(o0, o1, o2, o3);
  }
}

extern "C" void kernel_launch(void* const* d_in, const int* in_sizes, int n_in,
                              void* d_out, int out_size, void* d_ws, size_t ws_size,
                              hipStream_t stream) {
  const float* x  = (const float*)d_in[0];
  const int*   ei = (const int*)d_in[1];
  const float* W1 = (const float*)d_in[2];
  const float* b1 = (const float*)d_in[3];
  const float* W2 = (const float*)d_in[4];
  const float* b2 = (const float*)d_in[5];
  float* out = (float*)d_out;

  const int F = 128;
  const int N = in_sizes[0] / F;
  const int E = in_sizes[1] / 2;
  const int* rows = ei;       // edge_index[0] = source
  const int* cols = ei + E;   // edge_index[1] = destination

  // workspace layout (~55 MB)
  u16*   bufXW  = (u16*)d_ws;                      // N*128 bf16 (xws scratch)
  u16*   bufH   = bufXW + (size_t)N * F;           // N*128 bf16 (h)
  float* dinv   = (float*)(bufH + (size_t)N * F);  // N f32
  int*   cnt    = (int*)(dinv + N);                // N i32 (count, then cursor)
  int*   rowptr = cnt + N;                         // N+1 i32
  int*   adj    = rowptr + (N + 1);                // E i32
  int*   bsum   = adj + E;                         // 128 i32
  int*   bsum2  = bsum + 128;                      // 128 i32
  u16*   Wt1    = (u16*)(bsum2 + 128);             // 128*128 bf16 (W1^T)
  u16*   Wt2    = Wt1 + 128 * 128;                 // 128*128 bf16 (W2^T)

  const int NB = (N + 1023) / 1024;
  int eblocks = (E + 255) / 256;
  int nblocks = (N + 255) / 256;

  // build exact CSR + dinv; transpose/convert weights (11 dispatches total)
  zero_i32_kernel<<<nblocks, 256, 0, stream>>>(cnt, N);
  count_kernel<<<eblocks, 256, 0, stream>>>(cols, rows, cnt, E, N);
  wt_kernel<<<128, 256, 0, stream>>>(W1, W2, Wt1, Wt2);
  scan1_kernel<<<NB, 256, 0, stream>>>(cnt, rowptr, bsum, dinv, N);
  scan2_kernel<<<1, 128, 0, stream>>>(bsum, bsum2, rowptr, NB, N);
  scan3_kernel<<<NB, 256, 0, stream>>>(rowptr, bsum2, N);
  fill_kernel<<<eblocks, 256, 0, stream>>>(cols, rows, rowptr, cnt, adj, E, N);

  int gblocks = (N + 127) / 128;
  int ablocks = (N + 7) / 8;
  // layer 1: xws1 = dinv ⊙ (x@W1) (bf16) ; h = relu(dinv⊙Σ + b1) -> bufH (bf16)
  gemm_mfma_kernel<0><<<gblocks, 256, 0, stream>>>(x, Wt1, dinv, bufXW, N);
  aggregate_kernel<1, 1><<<ablocks, 256, 0, stream>>>(
      (const uint2*)bufXW, rowptr, adj, dinv, b1, bufH, N);
  // layer 2: xws2 = dinv ⊙ (h@W2) (bf16) ; out = dinv⊙Σ + b2 -> d_out (fp32)
  gemm_mfma_kernel<1><<<gblocks, 256, 0, stream>>>(bufH, Wt2, dinv, bufXW, N);
  aggregate_kernel<0, 0><<<ablocks, 256, 0, stream>>>(
      (const uint2*)bufXW, rowptr, adj, dinv, b2, out, N);
}

// Round 6
// 261.918 us; speedup vs baseline: 1.7942x; 1.0322x over previous
//
#include <hip/hip_runtime.h>
#include <cstdint>
#include <cstddef>

// GCN 2-layer:
//   h   = relu(Agg(x@W1) + b1);  out = Agg(h@W2) + b2
//   Agg(z)[i] = dinv[i] * ( dinv[i]*z[i] + sum_{e: col(e)=i} dinv[row(e)]*z[row(e)] )
//   dinv[i] = rsqrt(1 + indeg(i))
// Factorization: xws = dinv ⊙ (A@W) (scaled in GEMM epilogue, bf16);
//   Agg reduces to out[i] = dinv[i]*(xws[i] + Σ_{nbr r} xws[r]) + b.
// GEMM on MFMA (bf16 in, fp32 acc), coalesced epilogue via LDS transpose.
// CSR built exactly each call (count -> scan -> fill) -> no uninit adj reads.
// Aggregate: quarter-wave (16 lanes) per node, uint4 (8 bf16) per lane,
// unroll-8 -> 4 chains x 8 outstanding 16B gathers per wave (latency-bound).

typedef unsigned int u32;
typedef unsigned short u16;
typedef __attribute__((ext_vector_type(8))) short short8;   // 8 bf16 (4 VGPRs)
typedef __attribute__((ext_vector_type(4))) float f32x4;    // MFMA acc

__device__ __forceinline__ float bf2f(u32 lo16) {
  union { u32 u; float f; } c; c.u = lo16 << 16; return c.f;
}
__device__ __forceinline__ u32 f2bf(float f) {  // round-to-nearest-even
  union { float f; u32 u; } c; c.f = f;
  return (c.u + 0x7fffu + ((c.u >> 16) & 1u)) >> 16;
}

__global__ __launch_bounds__(256) void zero_i32_kernel(int* __restrict__ p, int n) {
  int i = blockIdx.x * 256 + threadIdx.x;
  if (i < n) p[i] = 0;
}

__global__ __launch_bounds__(256) void count_kernel(
    const int* __restrict__ cols, const int* __restrict__ rows,
    int* __restrict__ cnt, int E, int N) {
  int e = blockIdx.x * 256 + threadIdx.x;
  if (e >= E) return;
  int c = cols[e];
  int r = rows[e];
  if ((unsigned)c >= (unsigned)N || (unsigned)r >= (unsigned)N) return;
  atomicAdd(&cnt[c], 1);
}

// W1,W2 [k][n] fp32 -> Wt1,Wt2 [n][k] bf16, one launch (128 blocks)
__global__ __launch_bounds__(256) void wt_kernel(
    const float* __restrict__ W1, const float* __restrict__ W2,
    u16* __restrict__ Wt1, u16* __restrict__ Wt2) {
  int b = blockIdx.x;
  const float* W = (b < 64) ? W1 : W2;
  u16* Wt = (b < 64) ? Wt1 : Wt2;
  int idx = (b & 63) * 256 + threadIdx.x;  // 0..16383
  int k = idx >> 7, n = idx & 127;
  Wt[n * 128 + k] = (u16)f2bf(W[idx]);
}

// ---- exclusive scan of cnt[N] -> rowptr[N]; also emits dinv (fused)
__global__ __launch_bounds__(256) void scan1_kernel(
    const int* __restrict__ cnt, int* __restrict__ rowptr,
    int* __restrict__ bsum, float* __restrict__ dinv, int N) {
  __shared__ int sd[256];
  int t = threadIdx.x;
  int base = blockIdx.x * 1024 + t * 4;
  int c0 = (base + 0 < N) ? cnt[base + 0] : 0;
  int c1 = (base + 1 < N) ? cnt[base + 1] : 0;
  int c2 = (base + 2 < N) ? cnt[base + 2] : 0;
  int c3 = (base + 3 < N) ? cnt[base + 3] : 0;
  if (base + 0 < N) dinv[base + 0] = rsqrtf((float)c0 + 1.0f);
  if (base + 1 < N) dinv[base + 1] = rsqrtf((float)c1 + 1.0f);
  if (base + 2 < N) dinv[base + 2] = rsqrtf((float)c2 + 1.0f);
  if (base + 3 < N) dinv[base + 3] = rsqrtf((float)c3 + 1.0f);
  int s = c0 + c1 + c2 + c3;
  sd[t] = s;
  __syncthreads();
  for (int off = 1; off < 256; off <<= 1) {
    int v = (t >= off) ? sd[t - off] : 0;
    __syncthreads();
    sd[t] += v;
    __syncthreads();
  }
  int excl = sd[t] - s;
  if (base + 0 < N) rowptr[base + 0] = excl;
  if (base + 1 < N) rowptr[base + 1] = excl + c0;
  if (base + 2 < N) rowptr[base + 2] = excl + c0 + c1;
  if (base + 3 < N) rowptr[base + 3] = excl + c0 + c1 + c2;
  if (t == 255) bsum[blockIdx.x] = sd[255];
}

__global__ __launch_bounds__(128) void scan2_kernel(
    const int* __restrict__ bsum, int* __restrict__ bsum2,
    int* __restrict__ rowptr, int NB, int N) {
  __shared__ int sd[128];
  int t = threadIdx.x;
  int v = (t < NB) ? bsum[t] : 0;
  sd[t] = v;
  __syncthreads();
  for (int off = 1; off < 128; off <<= 1) {
    int u = (t >= off) ? sd[t - off] : 0;
    __syncthreads();
    sd[t] += u;
    __syncthreads();
  }
  bsum2[t] = sd[t] - v;
  if (t == NB - 1) rowptr[N] = sd[t];
}

__global__ __launch_bounds__(256) void scan3_kernel(
    int* __restrict__ rowptr, const int* __restrict__ bsum2, int N) {
  int t = threadIdx.x;
  int b = blockIdx.x;
  int base = b * 1024 + t * 4;
  int add = bsum2[b];
#pragma unroll
  for (int k = 0; k < 4; k++)
    if (base + k < N) rowptr[base + k] += add;
}

// cnt doubles as the cursor: atomicSub returns old count, pos = old-1 in [0,deg)
__global__ __launch_bounds__(256) void fill_kernel(
    const int* __restrict__ cols, const int* __restrict__ rows,
    const int* __restrict__ rowptr, int* __restrict__ cnt,
    int* __restrict__ adj, int E, int N) {
  int e = blockIdx.x * 256 + threadIdx.x;
  if (e >= E) return;
  int c = cols[e];
  int r = rows[e];
  if ((unsigned)c >= (unsigned)N || (unsigned)r >= (unsigned)N) return;
  int pos = atomicSub(&cnt[c], 1) - 1;
  if (pos >= 0) adj[rowptr[c] + pos] = r;
}

// C_bf16[M,128] = dinv[row] * (A[M,128] @ W[128,128]) via MFMA 16x16x32 bf16.
// Block = 256 thr (4 waves), tile 128 rows; wave w owns rows w*32..+31
// (2 m-tiles) x 128 cols (8 n-tiles). Wt staged once in LDS [n][k] pad 136.
// A fragments straight from global (each byte read once; no k-loop barrier).
// Epilogue: scaled bf16 tile round-trips through Ws (dead after k-loop) so
// global stores are coalesced uint4.
// Fragment layouts (m89/m118-verified):
//   A: lane holds A[m=lane&15][k=quad*8+j];  B: B[k=quad*8+j][n=lane&15]
//   C/D: col=lane&15, row=quad*4+reg
template <int A_BF16>
__global__ __launch_bounds__(256) void gemm_mfma_kernel(
    const void* __restrict__ Av, const u16* __restrict__ Wt,
    const float* __restrict__ dinv, u16* __restrict__ C, int M) {
  __shared__ u16 Ws[128][136];
  __shared__ float dv_s[128];
  const int tid = threadIdx.x;
  const int row0 = blockIdx.x * 128;

  {
    const uint4* src = (const uint4*)Wt;  // 2048 x 16B
#pragma unroll
    for (int i = 0; i < 8; i++) {
      int linear = tid + i * 256;
      int n = linear >> 4;
      int kq = linear & 15;
      *(uint4*)&Ws[n][kq * 8] = src[linear];
    }
  }
  if (tid < 128) {
    int gr = row0 + tid;
    dv_s[tid] = (gr < M) ? dinv[gr] : 0.f;
  }
  __syncthreads();

  const int wave = tid >> 6;
  const int lane = tid & 63;
  const int lm = lane & 15;
  const int quad = lane >> 4;
  const int m0 = wave * 32;

  f32x4 acc[2][8];
#pragma unroll
  for (int mt = 0; mt < 2; mt++)
#pragma unroll
    for (int nt = 0; nt < 8; nt++) acc[mt][nt] = (f32x4){0.f, 0.f, 0.f, 0.f};

#pragma unroll
  for (int k0 = 0; k0 < 128; k0 += 32) {
    short8 bfrag[8];
#pragma unroll
    for (int nt = 0; nt < 8; nt++)
      bfrag[nt] = *(const short8*)&Ws[nt * 16 + lm][k0 + quad * 8];

    short8 afrag[2];
#pragma unroll
    for (int mt = 0; mt < 2; mt++) {
      int gr = row0 + m0 + mt * 16 + lm;
      short8 f = (short8){0, 0, 0, 0, 0, 0, 0, 0};
      if (gr < M) {
        if (A_BF16) {
          f = *(const short8*)((const u16*)Av + (size_t)gr * 128 + k0 + quad * 8);
        } else {
          const float* Af = (const float*)Av + (size_t)gr * 128 + k0 + quad * 8;
          float4 v0 = *(const float4*)Af;
          float4 v1 = *(const float4*)(Af + 4);
          f[0] = (short)f2bf(v0.x); f[1] = (short)f2bf(v0.y);
          f[2] = (short)f2bf(v0.z); f[3] = (short)f2bf(v0.w);
          f[4] = (short)f2bf(v1.x); f[5] = (short)f2bf(v1.y);
          f[6] = (short)f2bf(v1.z); f[7] = (short)f2bf(v1.w);
        }
      }
      afrag[mt] = f;
    }

#pragma unroll
    for (int mt = 0; mt < 2; mt++)
#pragma unroll
      for (int nt = 0; nt < 8; nt++)
        acc[mt][nt] = __builtin_amdgcn_mfma_f32_16x16x32_bf16(
            afrag[mt], bfrag[nt], acc[mt][nt], 0, 0, 0);
  }

  // epilogue: scale by dinv[row], pack bf16 into Ws (dead), store coalesced
  __syncthreads();  // all waves done reading Ws
#pragma unroll
  for (int mt = 0; mt < 2; mt++) {
    int rbase = m0 + mt * 16 + quad * 4;
#pragma unroll
    for (int r = 0; r < 4; r++) {
      int lrow = rbase + r;
      float dv = dv_s[lrow];
#pragma unroll
      for (int nt = 0; nt < 8; nt++)
        Ws[lrow][nt * 16 + lm] = (u16)f2bf(acc[mt][nt][r] * dv);
    }
  }
  __syncthreads();
#pragma unroll
  for (int i = 0; i < 8; i++) {
    int linear = tid + i * 256;  // 0..2047
    int row = linear >> 4;
    int c8 = linear & 15;        // 8-col chunk
    int grow = row0 + row;
    if (grow < M)
      *(uint4*)(C + (size_t)grow * 128 + c8 * 8) = *(const uint4*)&Ws[row][c8 * 8];
  }
}

// Quarter-wave (16 lanes) per node; lane owns cols 8l..8l+7 (uint4 = 8 bf16).
// 4 independent node chains per wave + unroll-8 -> 32 outstanding 16B gathers.
template <int RELU, int OUT_BF16>
__global__ __launch_bounds__(256) void aggregate_kernel(
    const uint4* __restrict__ xws, const int* __restrict__ rowptr,
    const int* __restrict__ adj, const float* __restrict__ dinv,
    const float* __restrict__ bias, void* __restrict__ out, int N) {
  int node = blockIdx.x * 16 + (threadIdx.x >> 4);
  if (node >= N) return;
  int lane = threadIdx.x & 15;

  float a[8];
  {
    uint4 sv = xws[(size_t)node * 16 + lane];
    a[0] = bf2f(sv.x & 0xffff); a[1] = bf2f(sv.x >> 16);
    a[2] = bf2f(sv.y & 0xffff); a[3] = bf2f(sv.y >> 16);
    a[4] = bf2f(sv.z & 0xffff); a[5] = bf2f(sv.z >> 16);
    a[6] = bf2f(sv.w & 0xffff); a[7] = bf2f(sv.w >> 16);
  }

  int beg = rowptr[node];
  int end = rowptr[node + 1];
  for (int j = beg; j < end; j += 8) {
    int sidx[8];
    float msk[8];
#pragma unroll
    for (int k = 0; k < 8; k++) {
      int jj = j + k;
      int s = (jj < end) ? adj[jj] : -1;
      float m = 1.f;
      if ((unsigned)s >= (unsigned)N) { s = 0; m = 0.f; }
      sidx[k] = s;
      msk[k] = m;
    }
    uint4 v[8];
#pragma unroll
    for (int k = 0; k < 8; k++) v[k] = xws[(size_t)sidx[k] * 16 + lane];
#pragma unroll
    for (int k = 0; k < 8; k++) {
      a[0] = fmaf(msk[k], bf2f(v[k].x & 0xffff), a[0]);
      a[1] = fmaf(msk[k], bf2f(v[k].x >> 16), a[1]);
      a[2] = fmaf(msk[k], bf2f(v[k].y & 0xffff), a[2]);
      a[3] = fmaf(msk[k], bf2f(v[k].y >> 16), a[3]);
      a[4] = fmaf(msk[k], bf2f(v[k].z & 0xffff), a[4]);
      a[5] = fmaf(msk[k], bf2f(v[k].z >> 16), a[5]);
      a[6] = fmaf(msk[k], bf2f(v[k].w & 0xffff), a[6]);
      a[7] = fmaf(msk[k], bf2f(v[k].w >> 16), a[7]);
    }
  }

  float di = dinv[node];
  float4 b0 = ((const float4*)bias)[lane * 2];
  float4 b1 = ((const float4*)bias)[lane * 2 + 1];
  float o[8];
  o[0] = fmaf(di, a[0], b0.x); o[1] = fmaf(di, a[1], b0.y);
  o[2] = fmaf(di, a[2], b0.z); o[3] = fmaf(di, a[3], b0.w);
  o[4] = fmaf(di, a[4], b1.x); o[5] = fmaf(di, a[5], b1.y);
  o[6] = fmaf(di, a[6], b1.z); o[7] = fmaf(di, a[7], b1.w);
  if (RELU) {
#pragma unroll
    for (int k = 0; k < 8; k++) o[k] = fmaxf(o[k], 0.f);
  }
  if (OUT_BF16) {
    uint4 p;
    p.x = f2bf(o[0]) | (f2bf(o[1]) << 16);
    p.y = f2bf(o[2]) | (f2bf(o[3]) << 16);
    p.z = f2bf(o[4]) | (f2bf(o[5]) << 16);
    p.w = f2bf(o[6]) | (f2bf(o[7]) << 16);
    ((uint4*)out)[(size_t)node * 16 + lane] = p;
  } else {
    float4* op = (float4*)out + (size_t)node * 32 + lane * 2;
    op[0] = make_float4(o[0], o[1], o[2], o[3]);
    op[1] = make_float4(o[4], o[5], o[6], o[7]);
  }
}

extern "C" void kernel_launch(void* const* d_in, const int* in_sizes, int n_in,
                              void* d_out, int out_size, void* d_ws, size_t ws_size,
                              hipStream_t stream) {
  const float* x  = (const float*)d_in[0];
  const int*   ei = (const int*)d_in[1];
  const float* W1 = (const float*)d_in[2];
  const float* b1 = (const float*)d_in[3];
  const float* W2 = (const float*)d_in[4];
  const float* b2 = (const float*)d_in[5];
  float* out = (float*)d_out;

  const int F = 128;
  const int N = in_sizes[0] / F;
  const int E = in_sizes[1] / 2;
  const int* rows = ei;       // edge_index[0] = source
  const int* cols = ei + E;   // edge_index[1] = destination

  // workspace layout (~55 MB)
  u16*   bufXW  = (u16*)d_ws;                      // N*128 bf16 (xws scratch)
  u16*   bufH   = bufXW + (size_t)N * F;           // N*128 bf16 (h)
  float* dinv   = (float*)(bufH + (size_t)N * F);  // N f32
  int*   cnt    = (int*)(dinv + N);                // N i32 (count, then cursor)
  int*   rowptr = cnt + N;                         // N+1 i32
  int*   adj    = rowptr + (N + 1);                // E i32
  int*   bsum   = adj + E;                         // 128 i32
  int*   bsum2  = bsum + 128;                      // 128 i32
  u16*   Wt1    = (u16*)(bsum2 + 128);             // 128*128 bf16 (W1^T)
  u16*   Wt2    = Wt1 + 128 * 128;                 // 128*128 bf16 (W2^T)

  const int NB = (N + 1023) / 1024;
  int eblocks = (E + 255) / 256;
  int nblocks = (N + 255) / 256;

  // build exact CSR + dinv; transpose/convert weights
  zero_i32_kernel<<<nblocks, 256, 0, stream>>>(cnt, N);
  count_kernel<<<eblocks, 256, 0, stream>>>(cols, rows, cnt, E, N);
  wt_kernel<<<128, 256, 0, stream>>>(W1, W2, Wt1, Wt2);
  scan1_kernel<<<NB, 256, 0, stream>>>(cnt, rowptr, bsum, dinv, N);
  scan2_kernel<<<1, 128, 0, stream>>>(bsum, bsum2, rowptr, NB, N);
  scan3_kernel<<<NB, 256, 0, stream>>>(rowptr, bsum2, N);
  fill_kernel<<<eblocks, 256, 0, stream>>>(cols, rows, rowptr, cnt, adj, E, N);

  int gblocks = (N + 127) / 128;
  int ablocks = (N + 15) / 16;
  // layer 1: xws1 = dinv ⊙ (x@W1) (bf16) ; h = relu(dinv⊙Σ + b1) -> bufH (bf16)
  gemm_mfma_kernel<0><<<gblocks, 256, 0, stream>>>(x, Wt1, dinv, bufXW, N);
  aggregate_kernel<1, 1><<<ablocks, 256, 0, stream>>>(
      (const uint4*)bufXW, rowptr, adj, dinv, b1, bufH, N);
  // layer 2: xws2 = dinv ⊙ (h@W2) (bf16) ; out = dinv⊙Σ + b2 -> d_out (fp32)
  gemm_mfma_kernel<1><<<gblocks, 256, 0, stream>>>(bufH, Wt2, dinv, bufXW, N);
  aggregate_kernel<0, 0><<<ablocks, 256, 0, stream>>>(
      (const uint4*)bufXW, rowptr, adj, dinv, b2, out, N);
}